// Round 1
// baseline (1961.342 us; speedup 1.0000x reference)
//
#include <hip/hip_runtime.h>
#include <math.h>

#define BB 128   // batch
#define SS 128   // seq len
#define EE 300   // embed dim
#define HH 256   // per-direction hidden
#define G4 1024  // 4*HH gate width
#define TT 16    // tagset
#define NEGV -10000.0f
#define START_TAG 14
#define STOP_TAG 15

__device__ __forceinline__ float sigm(float x) { return 1.0f / (1.0f + expf(-x)); }

// ---------------- prep: weight transposes + bias folding ----------------
// WihT[d][e][j] = Wih_d[j][e]           (2*300*1024)
// Whh4[d][k][u*4+g] = Whh_d[g*256+u][k] (2*256*1024)  -> float4 per (k,u)
// bsum[d][j] = bih_d[j] + bhh_d[j]      (2*1024)
__global__ void k_prep(const float* __restrict__ Wih_f, const float* __restrict__ Whh_f,
                       const float* __restrict__ bih_f, const float* __restrict__ bhh_f,
                       const float* __restrict__ Wih_b, const float* __restrict__ Whh_b,
                       const float* __restrict__ bih_b, const float* __restrict__ bhh_b,
                       float* __restrict__ WihT, float* __restrict__ Whh4,
                       float* __restrict__ bsum) {
  int id = blockIdx.x * blockDim.x + threadIdx.x;
  const int N1 = 2 * EE * G4;
  const int N2 = 2 * HH * G4;
  const int N3 = 2 * G4;
  if (id < N1) {
    int d = id / (EE * G4); int r = id % (EE * G4);
    int e = r / G4; int j = r % G4;
    const float* W = d ? Wih_b : Wih_f;
    WihT[id] = W[j * EE + e];
  } else if (id < N1 + N2) {
    int t = id - N1;
    int d = t / (HH * G4); int r = t % (HH * G4);
    int k = r / G4; int q = r % G4; int u = q >> 2; int g = q & 3;
    const float* W = d ? Whh_b : Whh_f;
    Whh4[t] = W[(g * HH + u) * HH + k];
  } else if (id < N1 + N2 + N3) {
    int t = id - N1 - N2;
    int d = t / G4; int j = t % G4;
    bsum[t] = d ? (bih_b[j] + bhh_b[j]) : (bih_f[j] + bhh_f[j]);
  }
}

// ---------------- input projection GEMM (gathered) ----------------
// xproj[d][s][b][j] = bsum[d][j] + sum_e emb[sent[b][s]][e] * Wih_d[j][e]
// grid: 2 dirs * 1024 sb-tiles (16 (s,b) pairs each), 256 threads
__global__ void k_xproj(const int* __restrict__ sent, const float* __restrict__ emb,
                        const float* __restrict__ WihT, const float* __restrict__ bsum,
                        float* __restrict__ xproj) {
  __shared__ float xs[16][EE];
  __shared__ int idxs[16];
  int blk = blockIdx.x;
  int d = blk >> 10;
  int tile = blk & 1023;
  int tid = threadIdx.x;
  if (tid < 16) {
    int sb = tile * 16 + tid;
    int s = sb >> 7, b = sb & 127;
    idxs[tid] = sent[b * SS + s];
  }
  __syncthreads();
  for (int t = tid; t < 16 * EE; t += 256) {
    int i = t / EE, e = t % EE;
    xs[i][e] = emb[(size_t)idxs[i] * EE + e];
  }
  __syncthreads();

  const float* WT = WihT + (size_t)d * EE * G4;
  float acc0[16], acc1[16], acc2[16], acc3[16];
#pragma unroll
  for (int i = 0; i < 16; ++i) { acc0[i] = 0.f; acc1[i] = 0.f; acc2[i] = 0.f; acc3[i] = 0.f; }

  for (int e = 0; e < EE; ++e) {
    const float* row = WT + (size_t)e * G4;
    float w0 = row[tid];
    float w1 = row[tid + 256];
    float w2 = row[tid + 512];
    float w3 = row[tid + 768];
#pragma unroll
    for (int i = 0; i < 16; ++i) {
      float x = xs[i][e];
      acc0[i] += w0 * x; acc1[i] += w1 * x; acc2[i] += w2 * x; acc3[i] += w3 * x;
    }
  }
  float b0 = bsum[d * G4 + tid];
  float b1 = bsum[d * G4 + tid + 256];
  float b2 = bsum[d * G4 + tid + 512];
  float b3 = bsum[d * G4 + tid + 768];
#pragma unroll
  for (int i = 0; i < 16; ++i) {
    int sb = tile * 16 + i;
    int s = sb >> 7, b = sb & 127;
    float* xp = xproj + (((size_t)d * SS + s) * BB + b) * G4;
    xp[tid]       = acc0[i] + b0;
    xp[tid + 256] = acc1[i] + b1;
    xp[tid + 512] = acc2[i] + b2;
    xp[tid + 768] = acc3[i] + b3;
  }
}

// ---------------- recurrent LSTM (both dirs), feats fused ----------------
// grid 128: d = blk>>6, pair = blk&63 -> b0=2*pair, b1=b0+1. 256 threads = hidden unit u.
// featsP[d][b][s][t] = sum_u h_d[s][b][u] * W_out[t][d*256+u]
__global__ void k_recur(const float* __restrict__ xproj, const float* __restrict__ Whh4,
                        const float* __restrict__ Wout, const float* __restrict__ h0,
                        const float* __restrict__ c0, float* __restrict__ featsP) {
  __shared__ float h0s[HH], h1s[HH];
  __shared__ float Wo[TT][HH];
  int d = blockIdx.x >> 6;
  int pair = blockIdx.x & 63;
  int b0 = pair * 2, b1 = b0 + 1;
  int u = threadIdx.x;

#pragma unroll
  for (int t = 0; t < TT; ++t) Wo[t][u] = Wout[t * 512 + d * HH + u];
  h0s[u] = h0[((size_t)d * BB + b0) * HH + u];
  h1s[u] = h0[((size_t)d * BB + b1) * HH + u];
  float c0r = c0[((size_t)d * BB + b0) * HH + u];
  float c1r = c0[((size_t)d * BB + b1) * HH + u];
  __syncthreads();

  const float4* W4 = (const float4*)(Whh4 + (size_t)d * HH * G4);

  for (int step = 0; step < SS; ++step) {
    int s = d ? (SS - 1 - step) : step;
    const float* xp0 = xproj + (((size_t)d * SS + s) * BB + b0) * G4;
    const float* xp1 = xp0 + G4;
    float ai0 = xp0[u], af0 = xp0[u + 256], ag0 = xp0[u + 512], ao0 = xp0[u + 768];
    float ai1 = xp1[u], af1 = xp1[u + 256], ag1 = xp1[u + 512], ao1 = xp1[u + 768];

#pragma unroll 4
    for (int k = 0; k < HH; ++k) {
      float4 w = W4[k * HH + u];
      float hk0 = h0s[k], hk1 = h1s[k];
      ai0 += w.x * hk0; af0 += w.y * hk0; ag0 += w.z * hk0; ao0 += w.w * hk0;
      ai1 += w.x * hk1; af1 += w.y * hk1; ag1 += w.z * hk1; ao1 += w.w * hk1;
    }
    c0r = sigm(af0) * c0r + sigm(ai0) * tanhf(ag0);
    float h0n = sigm(ao0) * tanhf(c0r);
    c1r = sigm(af1) * c1r + sigm(ai1) * tanhf(ag1);
    float h1n = sigm(ao1) * tanhf(c1r);

    __syncthreads();
    h0s[u] = h0n;
    h1s[u] = h1n;
    __syncthreads();

    // feats partial: 16 threads per tag t, each sums 16 units, shfl-reduce
    int t = u >> 4, l = u & 15;
    float p0 = 0.f, p1 = 0.f;
#pragma unroll
    for (int q = 0; q < 16; ++q) {
      int uu = l * 16 + q;
      float w = Wo[t][uu];
      p0 += w * h0s[uu];
      p1 += w * h1s[uu];
    }
#pragma unroll
    for (int off = 8; off; off >>= 1) {
      p0 += __shfl_down(p0, off, 16);
      p1 += __shfl_down(p1, off, 16);
    }
    if (l == 0) {
      featsP[(((size_t)d * BB + b0) * SS + s) * TT + t] = p0;
      featsP[(((size_t)d * BB + b1) * SS + s) * TT + t] = p1;
    }
  }
}

// ---------------- Viterbi ----------------
// grid 8 x 256 threads: 16 batch rows per block, 16 lanes per row (lane = next tag)
__global__ void k_viterbi(const float* __restrict__ featsP, const float* __restrict__ b_out,
                          const float* __restrict__ trans, float* __restrict__ out,
                          unsigned char* __restrict__ bp) {
  __shared__ float tr[TT * TT];
  int tid = threadIdx.x;
  if (tid < TT * TT) tr[tid] = trans[tid];
  __syncthreads();

  int bg = tid >> 4;
  int next = tid & 15;
  int b = blockIdx.x * 16 + bg;
  float fv = (next == START_TAG) ? 0.0f : NEGV;
  float bo = b_out[next];
  const float* fp0 = featsP + ((size_t)b * SS) * TT;              // d=0
  const float* fp1 = featsP + (((size_t)BB + b) * SS) * TT;       // d=1

  for (int s = 0; s < SS; ++s) {
    float best = -INFINITY; int arg = 0;
#pragma unroll
    for (int prev = 0; prev < TT; ++prev) {
      float fvp = __shfl(fv, prev, 16);
      float cand = fvp + tr[next * TT + prev];
      if (cand > best) { best = cand; arg = prev; }
    }
    float feat = fp0[s * TT + next] + fp1[s * TT + next] + bo;
    fv = best + feat;
    bp[((size_t)b * SS + s) * TT + next] = (unsigned char)arg;
  }

  float bv = fv + tr[STOP_TAG * TT + next];
  int bi = next;
#pragma unroll
  for (int off = 8; off; off >>= 1) {
    float ov = __shfl_down(bv, off, 16);
    int oi = __shfl_down(bi, off, 16);
    if (ov > bv || (ov == bv && oi < bi)) { bv = ov; bi = oi; }
  }
  if (next == 0) {
    out[b] = bv;
    int tag = bi;
    float* po = out + BB + (size_t)b * SS;
    for (int s = SS - 1; s >= 0; --s) {
      po[s] = (float)tag;
      tag = bp[((size_t)b * SS + s) * TT + tag];
    }
  }
}

// ---------------- host ----------------
extern "C" void kernel_launch(void* const* d_in, const int* in_sizes, int n_in,
                              void* d_out, int out_size, void* d_ws, size_t ws_size,
                              hipStream_t stream) {
  const int*   sent  = (const int*)d_in[0];
  const float* emb   = (const float*)d_in[1];
  const float* Wih_f = (const float*)d_in[2];
  const float* Whh_f = (const float*)d_in[3];
  const float* bih_f = (const float*)d_in[4];
  const float* bhh_f = (const float*)d_in[5];
  const float* Wih_b = (const float*)d_in[6];
  const float* Whh_b = (const float*)d_in[7];
  const float* bih_b = (const float*)d_in[8];
  const float* bhh_b = (const float*)d_in[9];
  const float* Wout  = (const float*)d_in[10];
  const float* b_out = (const float*)d_in[11];
  const float* trans = (const float*)d_in[12];
  const float* h0    = (const float*)d_in[13];
  const float* c0    = (const float*)d_in[14];

  float* ws = (float*)d_ws;
  size_t off = 0;
  float* xproj  = ws + off; off += (size_t)2 * SS * BB * G4;   // 33,554,432 fl
  float* WihT   = ws + off; off += (size_t)2 * EE * G4;        //    614,400 fl
  float* Whh4   = ws + off; off += (size_t)2 * HH * G4;        //    524,288 fl
  float* bsum   = ws + off; off += (size_t)2 * G4;             //      2,048 fl
  float* featsP = ws + off; off += (size_t)2 * BB * SS * TT;   //    524,288 fl
  unsigned char* bp = (unsigned char*)(ws + off);              //    262,144 B

  const int NPREP = 2*EE*G4 + 2*HH*G4 + 2*G4;
  k_prep<<<(NPREP + 255) / 256, 256, 0, stream>>>(Wih_f, Whh_f, bih_f, bhh_f,
                                                  Wih_b, Whh_b, bih_b, bhh_b,
                                                  WihT, Whh4, bsum);
  k_xproj<<<2048, 256, 0, stream>>>(sent, emb, WihT, bsum, xproj);
  k_recur<<<128, 256, 0, stream>>>(xproj, Whh4, Wout, h0, c0, featsP);
  k_viterbi<<<8, 256, 0, stream>>>(featsP, b_out, trans, (float*)d_out, bp);
}